// Round 4
// baseline (469.147 us; speedup 1.0000x reference)
//
#include <hip/hip_runtime.h>

// PLIF: v[t] = zero-reset( v[t-1]*decay + x[t] ), reset at v >= 1.0.
// T=16, spatial = N*C*H*W = 4194304 elements -> 256 MiB in + 256 MiB out.
//
// Round-4: the 16-deep load pipeline is pinned with a SINGLE asm volatile
// consuming ALL 16 loaded values as tied operands. History of this fight:
//   r1: prefetch pair          -> sunk (VGPR 28)
//   r2: sched_barrier(0)       -> IR sinking crossed it (VGPR 36)
//   r3: per-value asm pins     -> loads interleaved between the separate
//                                 asm statements (VGPR 40)
// A single asm reading all 16 registers admits no interleave: every load
// must be issued and completed before it, so all 64 VGPRs of x-data are
// simultaneously live (expect VGPR >= 80 -- that's the validity tell).
//
// Resulting shape per wave: 16 independent global_load_dwordx4 (16 KB in
// flight), one bulk s_waitcnt, then 16 fma+nt-store steps. Stores are
// younger than nothing that blocks them; cross-wave overlap covers the
// store phase (bulk-synchronous copy-kernel structure).

#define T_STEPS 16
#define V_THRESHOLD 1.0f

typedef float f32x4 __attribute__((ext_vector_type(4)));

__global__ __launch_bounds__(256) void plif_kernel(
    const f32x4* __restrict__ x,      // [T, SPATIAL/4]
    const float* __restrict__ decay,  // [1]
    f32x4*       __restrict__ out,    // [T, SPATIAL/4]
    long long    stride4)             // SPATIAL/4
{
    const long long col = (long long)blockIdx.x * blockDim.x + threadIdx.x;
    if (col >= stride4) return;
    const float d = decay[0];

    // ---- Phase 1: issue all T loads back-to-back (independent addresses).
    f32x4 xs[T_STEPS];
#pragma unroll
    for (int t = 0; t < T_STEPS; ++t)
        xs[t] = x[col + (long long)t * stride4];

    // ---- Pin: ONE asm consuming all 16 values. No load can sink past
    // this, and no pairwise interleave is possible (r3's failure mode).
    asm volatile(""
                 : "+v"(xs[0]),  "+v"(xs[1]),  "+v"(xs[2]),  "+v"(xs[3]),
                   "+v"(xs[4]),  "+v"(xs[5]),  "+v"(xs[6]),  "+v"(xs[7]),
                   "+v"(xs[8]),  "+v"(xs[9]),  "+v"(xs[10]), "+v"(xs[11]),
                   "+v"(xs[12]), "+v"(xs[13]), "+v"(xs[14]), "+v"(xs[15]));

    // ---- Phase 2: register scan; all data already in VGPRs.
    f32x4 v = (f32x4)0.f;
    long long off = col;
#pragma unroll
    for (int t = 0; t < T_STEPS; ++t) {
        const f32x4 xv = xs[t];
        v.x = fmaf(v.x, d, xv.x); if (v.x >= V_THRESHOLD) v.x = 0.f;
        v.y = fmaf(v.y, d, xv.y); if (v.y >= V_THRESHOLD) v.y = 0.f;
        v.z = fmaf(v.z, d, xv.z); if (v.z >= V_THRESHOLD) v.z = 0.f;
        v.w = fmaf(v.w, d, xv.w); if (v.w >= V_THRESHOLD) v.w = 0.f;
        __builtin_nontemporal_store(v, &out[off]);
        off += stride4;
    }
}

extern "C" void kernel_launch(void* const* d_in, const int* in_sizes, int n_in,
                              void* d_out, int out_size, void* d_ws, size_t ws_size,
                              hipStream_t stream) {
    const float* x     = (const float*)d_in[0];   // [T,N,C,H,W] fp32
    const float* decay = (const float*)d_in[1];   // [1] fp32
    float* out         = (float*)d_out;           // [T,N,C,H,W] fp32

    const long long total   = in_sizes[0];        // T * SPATIAL
    const long long spatial = total / T_STEPS;    // 4194304
    const long long stride4 = spatial / 4;        // 1048576 float4/timestep

    const int block = 256;
    const int grid  = (int)((stride4 + block - 1) / block);  // 4096

    plif_kernel<<<grid, block, 0, stream>>>(
        (const f32x4*)x, decay, (f32x4*)out, stride4);
}